// Round 5
// baseline (639.289 us; speedup 1.0000x reference)
//
#include <hip/hip_runtime.h>
#include <cmath>
#include <cstdint>

namespace {

constexpr int kLevels = 8;
constexpr uint32_t kT = 1u << 16;
constexpr uint32_t kPrime1 = 2654435761u;
constexpr uint32_t kPrime2 = 805459861u;

struct LevelParams {
    float scale[kLevels];
    uint32_t res[kLevels];
    uint32_t hashed_mask;
};

// Fused encode+MLP. Encode carries enc as 8 packed bf16x2 regs (round-4's
// encode kernel proved this loop body fits 64 VGPR); MLP unpacks once.
// min 7 waves/EU -> ~73 VGPR cap: headroom above the proven 64 so no spill
// (rounds 2/3 showed a forced too-tight cap costs 5x in scratch traffic).
__global__ __launch_bounds__(256, 7) void ngp_fused_kernel(
    const float* __restrict__ uvi,
    const float* __restrict__ table,
    const float* __restrict__ W1,
    const float* __restrict__ b1,
    const float* __restrict__ W2,
    const float* __restrict__ b2,
    float* __restrict__ out,
    int n, LevelParams lp)
{
    const int i = blockIdx.x * blockDim.x + threadIdx.x;
    if (i >= n) return;

    const float ux = uvi[3 * i + 0];
    const float uy = uvi[3 * i + 1];
    const float uz = uvi[3 * i + 2];

    const float2* __restrict__ tb = reinterpret_cast<const float2*>(table);

    uint32_t packed[kLevels];

    #pragma unroll
    for (int l = 0; l < kLevels; ++l) {
        const float s = lp.scale[l];
        const float px = fmaf(ux, s, 0.5f);
        const float py = fmaf(uy, s, 0.5f);
        const float pz = fmaf(uz, s, 0.5f);
        const float fx = floorf(px), fy = floorf(py), fz = floorf(pz);
        const float wx = px - fx, wy = py - fy, wz = pz - fz;
        const uint32_t x0 = (uint32_t)fx, y0 = (uint32_t)fy, z0 = (uint32_t)fz;

        const bool hashed = (lp.hashed_mask >> l) & 1u;

        uint32_t hx0, hx1, hy0, hy1, hz0, hz1;
        if (hashed) {
            hx0 = x0;             hx1 = x0 + 1u;
            hy0 = y0 * kPrime1;   hy1 = hy0 + kPrime1;
            hz0 = z0 * kPrime2;   hz1 = hz0 + kPrime2;
        } else {
            const uint32_t r  = lp.res[l];
            const uint32_t r2 = r * r;
            hx0 = x0;             hx1 = x0 + 1u;
            hy0 = y0 * r;         hy1 = hy0 + r;
            hz0 = z0 * r2;        hz1 = hz0 + r2;
        }

        const float wx0 = 1.f - wx, wy0 = 1.f - wy, wz0 = 1.f - wz;
        const float w00 = wx0 * wy0;
        const float w10 = wx  * wy0;
        const float w01 = wx0 * wy;
        const float w11 = wx  * wy;

        const uint32_t base = (uint32_t)l << 16;
        float a0 = 0.f, a1 = 0.f;

        #pragma unroll
        for (int c = 0; c < 8; ++c) {
            const uint32_t hx = (c & 1) ? hx1 : hx0;
            const uint32_t hy = (c & 2) ? hy1 : hy0;
            const uint32_t hz = (c & 4) ? hz1 : hz0;
            uint32_t idxc;
            if (hashed) idxc = (hx ^ hy ^ hz) & (kT - 1u);
            else        idxc = hx + hy + hz;
            const float wxy = (c & 2) ? ((c & 1) ? w11 : w01)
                                      : ((c & 1) ? w10 : w00);
            const float wcc = wxy * ((c & 4) ? wz : wz0);
            const float2 t = tb[base + idxc];
            a0 = fmaf(t.x, wcc, a0);
            a1 = fmaf(t.y, wcc, a1);
        }
        // truncate-to-bf16 pack (validated round 4: absmax 0.0)
        packed[l] = (__float_as_uint(a0) >> 16) |
                    (__float_as_uint(a1) & 0xFFFF0000u);
    }

    // unpack once; encode-loop registers are dead here
    float enc[16];
    #pragma unroll
    for (int l = 0; l < kLevels; ++l) {
        enc[2 * l + 0] = __uint_as_float(packed[l] << 16);
        enc[2 * l + 1] = __uint_as_float(packed[l] & 0xFFFF0000u);
    }

    // MLP: W1/b1/W2 at compile-time indices -> uniform scalar loads
    float logit = b2[0];
    #pragma unroll
    for (int j = 0; j < 64; ++j) {
        float h = b1[j];
        #pragma unroll
        for (int k = 0; k < 16; ++k)
            h = fmaf(enc[k], W1[k * 64 + j], h);
        h = fmaxf(h, 0.f);
        logit = fmaf(h, W2[j], logit);
    }

    out[i] = 1.f / (1.f + __expf(-logit));
}

} // namespace

extern "C" void kernel_launch(void* const* d_in, const int* in_sizes, int n_in,
                              void* d_out, int out_size, void* d_ws, size_t ws_size,
                              hipStream_t stream)
{
    const float* uvi   = (const float*)d_in[0];
    const float* table = (const float*)d_in[1];
    const float* W1    = (const float*)d_in[2];
    const float* b1    = (const float*)d_in[3];
    const float* W2    = (const float*)d_in[4];
    const float* b2    = (const float*)d_in[5];
    float* out = (float*)d_out;

    const int n = in_sizes[0] / 3;

    // Replicate numpy's double-precision level math exactly.
    LevelParams lp;
    const double B = exp(log(2048.0 / 16.0) / (double)(kLevels - 1));
    uint32_t mask = 0;
    for (int l = 0; l < kLevels; ++l) {
        const double scale_d = 16.0 * pow(B, (double)l) - 1.0;
        const long long res = (long long)ceil(scale_d) + 1;
        lp.scale[l] = (float)scale_d;
        lp.res[l]   = (uint32_t)res;
        if (res * res * res > (long long)kT) mask |= (1u << l);
    }
    lp.hashed_mask = mask;

    dim3 block(256);
    dim3 grid((unsigned)((n + 255) / 256));
    hipLaunchKernelGGL(ngp_fused_kernel, grid, block, 0, stream,
                       uvi, table, W1, b1, W2, b2, out, n, lp);
}

// Round 6
// 387.960 us; speedup vs baseline: 1.6478x; 1.6478x over previous
//
#include <hip/hip_runtime.h>
#include <cmath>
#include <cstdint>

namespace {

constexpr int kLevels = 8;
constexpr uint32_t kT = 1u << 16;
constexpr uint32_t kPrime1 = 2654435761u;
constexpr uint32_t kPrime2 = 805459861u;

// level 0: res=16, corners reach 16 -> max dense idx = 16*(1+16+256) = 4368
constexpr uint32_t kL0Entries = 4369;

struct LevelParams {
    float scale[kLevels];
    uint32_t res[kLevels];
    uint32_t hashed_mask;
};

// Fused encode+MLP.
//  - enc carried as 8 packed bf16x2 regs through encode (round-4's encode
//    kernel proved this body settles at 64 VGPR naturally).
//  - NO min-waves launch hint: rounds 2/3/5 proved any forced cap spills
//    (36..64 VGPR + 0.3..0.9 GB scratch traffic, 5x slowdown).
//  - level 0 (dense, 4369 entries) staged in 17.5 KB LDS as bf16x2:
//    8 of 64 gathers leave the divergent-global/TA pipe.
__global__ __launch_bounds__(256) void ngp_fused_kernel(
    const float* __restrict__ uvi,
    const float* __restrict__ table,
    const float* __restrict__ W1,
    const float* __restrict__ b1,
    const float* __restrict__ W2,
    const float* __restrict__ b2,
    float* __restrict__ out,
    int n, LevelParams lp)
{
    __shared__ uint32_t l0tab[kL0Entries];

    const float2* __restrict__ tb = reinterpret_cast<const float2*>(table);

    // stage level 0 as packed bf16x2 (truncation; validated rounds 4/5)
    for (uint32_t e = threadIdx.x; e < kL0Entries; e += blockDim.x) {
        const float2 t = tb[e];
        l0tab[e] = (__float_as_uint(t.x) >> 16) |
                   (__float_as_uint(t.y) & 0xFFFF0000u);
    }
    __syncthreads();

    const int i = blockIdx.x * blockDim.x + threadIdx.x;
    if (i >= n) return;

    const float ux = uvi[3 * i + 0];
    const float uy = uvi[3 * i + 1];
    const float uz = uvi[3 * i + 2];

    uint32_t packed[kLevels];

    #pragma unroll
    for (int l = 0; l < kLevels; ++l) {
        const float s = lp.scale[l];
        const float px = fmaf(ux, s, 0.5f);
        const float py = fmaf(uy, s, 0.5f);
        const float pz = fmaf(uz, s, 0.5f);
        const float fx = floorf(px), fy = floorf(py), fz = floorf(pz);
        const float wx = px - fx, wy = py - fy, wz = pz - fz;
        const uint32_t x0 = (uint32_t)fx, y0 = (uint32_t)fy, z0 = (uint32_t)fz;

        const bool hashed = (lp.hashed_mask >> l) & 1u;

        uint32_t hx0, hx1, hy0, hy1, hz0, hz1;
        if (hashed) {
            hx0 = x0;             hx1 = x0 + 1u;
            hy0 = y0 * kPrime1;   hy1 = hy0 + kPrime1;
            hz0 = z0 * kPrime2;   hz1 = hz0 + kPrime2;
        } else {
            const uint32_t r  = lp.res[l];
            const uint32_t r2 = r * r;
            hx0 = x0;             hx1 = x0 + 1u;
            hy0 = y0 * r;         hy1 = hy0 + r;
            hz0 = z0 * r2;        hz1 = hz0 + r2;
        }

        const float wx0 = 1.f - wx, wy0 = 1.f - wy, wz0 = 1.f - wz;
        const float w00 = wx0 * wy0;
        const float w10 = wx  * wy0;
        const float w01 = wx0 * wy;
        const float w11 = wx  * wy;

        float a0 = 0.f, a1 = 0.f;

        if (l == 0) {
            // dense level 0 from LDS (bf16x2)
            #pragma unroll
            for (int c = 0; c < 8; ++c) {
                const uint32_t hx = (c & 1) ? hx1 : hx0;
                const uint32_t hy = (c & 2) ? hy1 : hy0;
                const uint32_t hz = (c & 4) ? hz1 : hz0;
                const uint32_t idxc = hx + hy + hz;
                const float wxy = (c & 2) ? ((c & 1) ? w11 : w01)
                                          : ((c & 1) ? w10 : w00);
                const float wcc = wxy * ((c & 4) ? wz : wz0);
                const uint32_t wv = l0tab[idxc];
                a0 = fmaf(__uint_as_float(wv << 16), wcc, a0);
                a1 = fmaf(__uint_as_float(wv & 0xFFFF0000u), wcc, a1);
            }
        } else {
            const uint32_t base = (uint32_t)l << 16;
            #pragma unroll
            for (int c = 0; c < 8; ++c) {
                const uint32_t hx = (c & 1) ? hx1 : hx0;
                const uint32_t hy = (c & 2) ? hy1 : hy0;
                const uint32_t hz = (c & 4) ? hz1 : hz0;
                uint32_t idxc;
                if (hashed) idxc = (hx ^ hy ^ hz) & (kT - 1u);
                else        idxc = hx + hy + hz;
                const float wxy = (c & 2) ? ((c & 1) ? w11 : w01)
                                          : ((c & 1) ? w10 : w00);
                const float wcc = wxy * ((c & 4) ? wz : wz0);
                const float2 t = tb[base + idxc];
                a0 = fmaf(t.x, wcc, a0);
                a1 = fmaf(t.y, wcc, a1);
            }
        }
        packed[l] = (__float_as_uint(a0) >> 16) |
                    (__float_as_uint(a1) & 0xFFFF0000u);
    }

    // unpack once; encode-loop registers are dead here
    float enc[16];
    #pragma unroll
    for (int l = 0; l < kLevels; ++l) {
        enc[2 * l + 0] = __uint_as_float(packed[l] << 16);
        enc[2 * l + 1] = __uint_as_float(packed[l] & 0xFFFF0000u);
    }

    // MLP on float2 pairs (invites v_pk_fma_f32); weights at compile-time
    // indices -> uniform scalar loads.
    const float2* __restrict__ W1v = reinterpret_cast<const float2*>(W1);
    const float2* __restrict__ b1v = reinterpret_cast<const float2*>(b1);
    const float2* __restrict__ W2v = reinterpret_cast<const float2*>(W2);

    float logit = b2[0];
    #pragma unroll
    for (int j2 = 0; j2 < 32; ++j2) {
        float2 h = b1v[j2];
        #pragma unroll
        for (int k = 0; k < 16; ++k) {
            const float e = enc[k];
            const float2 w = W1v[k * 32 + j2];
            h.x = fmaf(e, w.x, h.x);
            h.y = fmaf(e, w.y, h.y);
        }
        h.x = fmaxf(h.x, 0.f);
        h.y = fmaxf(h.y, 0.f);
        const float2 w2 = W2v[j2];
        logit = fmaf(h.x, w2.x, logit);
        logit = fmaf(h.y, w2.y, logit);
    }

    out[i] = 1.f / (1.f + __expf(-logit));
}

} // namespace

extern "C" void kernel_launch(void* const* d_in, const int* in_sizes, int n_in,
                              void* d_out, int out_size, void* d_ws, size_t ws_size,
                              hipStream_t stream)
{
    const float* uvi   = (const float*)d_in[0];
    const float* table = (const float*)d_in[1];
    const float* W1    = (const float*)d_in[2];
    const float* b1    = (const float*)d_in[3];
    const float* W2    = (const float*)d_in[4];
    const float* b2    = (const float*)d_in[5];
    float* out = (float*)d_out;

    const int n = in_sizes[0] / 3;

    // Replicate numpy's double-precision level math exactly.
    LevelParams lp;
    const double B = exp(log(2048.0 / 16.0) / (double)(kLevels - 1));
    uint32_t mask = 0;
    for (int l = 0; l < kLevels; ++l) {
        const double scale_d = 16.0 * pow(B, (double)l) - 1.0;
        const long long res = (long long)ceil(scale_d) + 1;
        lp.scale[l] = (float)scale_d;
        lp.res[l]   = (uint32_t)res;
        if (res * res * res > (long long)kT) mask |= (1u << l);
    }
    lp.hashed_mask = mask;

    dim3 block(256);
    dim3 grid((unsigned)((n + 255) / 256));
    hipLaunchKernelGGL(ngp_fused_kernel, grid, block, 0, stream,
                       uvi, table, W1, b1, W2, b2, out, n, lp);
}